// Round 1
// baseline (392.010 us; speedup 1.0000x reference)
//
#include <hip/hip_runtime.h>

// Problem constants (from reference): FeatureT (8,128,256,256) f32, centerInit (2,128) f32
#define BB      8
#define CHN     128
#define NPIX    65536           // 256*256

// Output flat offsets (floats), concatenated in return order
#define OFF_CENTERS 0                       // [2,128]            = 256
#define OFF_LABELS  256                     // [8,1,256,256]      = 524288
#define OFF_ONEHOT  (256 + 524288)          // [8,2,256,256] raw  = 1048576
#define OFF_DISTS   (OFF_ONEHOT + 1048576)  // [8,2,256,256] raw  = 1048576
#define OFF_LABELT  (OFF_DISTS + 1048576)   // [8,1,256,256]      = 524288

// ws layout (doubles): [0..127] sum class0 per ch, [128..255] sum class1 per ch, [256] count1
#define WS_DOUBLES 257

// ---------------------------------------------------------------------------
// Pass 1: dists, labels, onehot for all 8 batches. 4 pixels per thread.
// ---------------------------------------------------------------------------
__global__ __launch_bounds__(256) void main_pass(
    const float* __restrict__ F, const float* __restrict__ C, float* __restrict__ out)
{
    __shared__ double c0s[CHN], c1s[CHN];
    const int t = threadIdx.x;
    // stage centers into LDS as doubles (broadcast reads later, conflict-free)
    if (t < 128)  c0s[t]       = (double)C[t];
    else          c1s[t - 128] = (double)C[t];   // C[128 + (t-128)]
    __syncthreads();

    const int tid = blockIdx.x * 256 + t;   // 0..131071
    const int b   = tid >> 14;              // 16384 threads per batch image
    const int p   = tid & 16383;            // float4 index within the image
    const int n0  = p << 2;                 // first pixel handled by this thread

    const float4* __restrict__ Fb = (const float4*)(F + (size_t)b * CHN * NPIX);

    // fp64 accumulation: argmin sign must match the fp64 numpy reference
    double d0[4] = {0.0, 0.0, 0.0, 0.0};
    double d1[4] = {0.0, 0.0, 0.0, 0.0};

    #pragma unroll 8
    for (int ch = 0; ch < CHN; ++ch) {
        float4 x = Fb[ch * (NPIX / 4) + p];     // coalesced: 16 B/lane
        double a0 = c0s[ch], a1 = c1s[ch];
        double x0 = (double)x.x, x1 = (double)x.y, x2 = (double)x.z, x3 = (double)x.w;
        d0[0] = fma(x0, a0, d0[0]);  d1[0] = fma(x0, a1, d1[0]);
        d0[1] = fma(x1, a0, d0[1]);  d1[1] = fma(x1, a1, d1[1]);
        d0[2] = fma(x2, a0, d0[2]);  d1[2] = fma(x2, a1, d1[2]);
        d0[3] = fma(x3, a0, d0[3]);  d1[3] = fma(x3, a1, d1[3]);
    }

    float labf[4], dist0[4], dist1[4];
    #pragma unroll
    for (int j = 0; j < 4; ++j) {
        double dd0 = 0.5 * (1.0 - d0[j]);
        double dd1 = 0.5 * (1.0 - d1[j]);
        // argmin with ties -> index 0: label 1 only if strictly smaller
        int lab = (dd1 < dd0) ? 1 : 0;
        labf[j]  = (float)lab;
        dist0[j] = (float)dd0;
        dist1[j] = (float)dd1;
    }

    float4 lab4 = make_float4(labf[0], labf[1], labf[2], labf[3]);
    *(float4*)(out + OFF_LABELS + b * NPIX + n0) = lab4;
    *(float4*)(out + OFF_LABELT + b * NPIX + n0) = lab4;

    // raw reshape [bb,N,2] -> [bb,2,w,h]: flat pos = b*2N + 2n + k (contiguous here)
    const size_t obase = (size_t)OFF_ONEHOT + (size_t)b * (2 * NPIX) + 2 * n0;
    *(float4*)(out + obase)     = make_float4(1.0f - labf[0], labf[0], 1.0f - labf[1], labf[1]);
    *(float4*)(out + obase + 4) = make_float4(1.0f - labf[2], labf[2], 1.0f - labf[3], labf[3]);

    const size_t dbase = (size_t)OFF_DISTS + (size_t)b * (2 * NPIX) + 2 * n0;
    *(float4*)(out + dbase)     = make_float4(dist0[0], dist1[0], dist0[1], dist1[1]);
    *(float4*)(out + dbase + 4) = make_float4(dist0[2], dist1[2], dist0[3], dist1[3]);
}

// ---------------------------------------------------------------------------
// Pass 2: per-channel, per-class sums over batch 7 (+ class-1 count).
// Grid: 256 blocks = (channel, half). Each block covers 32768 pixels.
// ---------------------------------------------------------------------------
__global__ __launch_bounds__(256) void sum_pass(
    const float* __restrict__ F, const float* __restrict__ out, double* __restrict__ ws)
{
    const int ch   = blockIdx.x >> 1;
    const int half = blockIdx.x & 1;
    const int t    = threadIdx.x;

    const float4* __restrict__ Fc = (const float4*)(F + (size_t)(7 * CHN + ch) * NPIX);
    const float4* __restrict__ L  = (const float4*)(out + OFF_LABELS + 7 * NPIX);

    double s_all = 0.0, s1 = 0.0;
    float  cntf  = 0.0f;

    const int base = half * (NPIX / 8) + t;   // float4 units; half covers 8192 float4
    #pragma unroll 4
    for (int i = 0; i < 32; ++i) {
        int idx = base + i * 256;
        float4 x = Fc[idx];
        float4 l = L[idx];                    // each component exactly 0.0 or 1.0
        s_all += (double)x.x + (double)x.y + (double)x.z + (double)x.w;
        // l*x is exact (multiply by 0 or 1)
        s1 += (double)(l.x * x.x) + (double)(l.y * x.y)
            + (double)(l.z * x.z) + (double)(l.w * x.w);
        cntf += l.x + l.y + l.z + l.w;
    }

    // wave64 reduce
    #pragma unroll
    for (int off = 32; off > 0; off >>= 1) {
        s_all += __shfl_down(s_all, off, 64);
        s1    += __shfl_down(s1,    off, 64);
        cntf  += __shfl_down(cntf,  off, 64);
    }

    __shared__ double redA[4], redS[4], redC[4];
    const int wave = t >> 6, lane = t & 63;
    if (lane == 0) { redA[wave] = s_all; redS[wave] = s1; redC[wave] = (double)cntf; }
    __syncthreads();
    if (t == 0) {
        double A  = redA[0] + redA[1] + redA[2] + redA[3];
        double S1 = redS[0] + redS[1] + redS[2] + redS[3];
        double CN = redC[0] + redC[1] + redC[2] + redC[3];
        atomicAdd(&ws[ch],       A - S1);   // class-0 channel sum
        atomicAdd(&ws[CHN + ch], S1);       // class-1 channel sum
        if (ch == 0) atomicAdd(&ws[256], CN);
    }
}

// ---------------------------------------------------------------------------
// Pass 3: centersIterout = centerInit + 0.001*(sum/(count+1) - centerInit)
// ---------------------------------------------------------------------------
__global__ __launch_bounds__(256) void final_pass(
    const float* __restrict__ C, const double* __restrict__ ws, float* __restrict__ out)
{
    const int t = threadIdx.x;      // 0..255 ; k = t>>7, ch = t&127
    double cnt1 = ws[256];
    double cnt0 = (double)NPIX - cnt1;
    double Num  = ((t < 128) ? cnt0 : cnt1) + 1.0;
    double ci   = ws[t] / Num;
    double c    = (double)C[t];
    out[OFF_CENTERS + t] = (float)(c + 0.001 * (ci - c));
}

extern "C" void kernel_launch(void* const* d_in, const int* in_sizes, int n_in,
                              void* d_out, int out_size, void* d_ws, size_t ws_size,
                              hipStream_t stream) {
    const float* F = (const float*)d_in[0];   // FeatureT (8,128,256,256)
    const float* C = (const float*)d_in[1];   // centerInit (2,128)
    // d_in[2], d_in[3] (num1,num2) are unused by the reference computation
    float*  out = (float*)d_out;
    double* ws  = (double*)d_ws;

    hipMemsetAsync(d_ws, 0, WS_DOUBLES * sizeof(double), stream);
    main_pass<<<dim3(512), dim3(256), 0, stream>>>(F, C, out);
    sum_pass<<<dim3(256), dim3(256), 0, stream>>>(F, out, ws);
    final_pass<<<dim3(1), dim3(256), 0, stream>>>(C, ws, out);
}

// Round 2
// 381.199 us; speedup vs baseline: 1.0284x; 1.0284x over previous
//
#include <hip/hip_runtime.h>

// Problem constants (from reference): FeatureT (8,128,256,256) f32, centerInit (2,128) f32
#define BB      8
#define CHN     128
#define NPIX    65536           // 256*256

// Output flat offsets (floats), concatenated in return order
#define OFF_CENTERS 0                       // [2,128]            = 256
#define OFF_LABELS  256                     // [8,1,256,256]      = 524288
#define OFF_ONEHOT  (256 + 524288)          // [8,2,256,256] raw  = 1048576
#define OFF_DISTS   (OFF_ONEHOT + 1048576)  // [8,2,256,256] raw  = 1048576
#define OFF_LABELT  (OFF_DISTS + 1048576)   // [8,1,256,256]      = 524288

// ---------------------------------------------------------------------------
// Pass 1: dists, labels, onehot for all 8 batches. 4 pixels per thread.
// Explicit 8-load batches so 8 global loads are in flight before the fp64
// compute consumes them (MLP >= 8 per wave).
// ---------------------------------------------------------------------------
__global__ __launch_bounds__(256) void main_pass(
    const float* __restrict__ F, const float* __restrict__ C, float* __restrict__ out)
{
    __shared__ double c0s[CHN], c1s[CHN];
    const int t = threadIdx.x;
    if (t < 128)  c0s[t]       = (double)C[t];
    else          c1s[t - 128] = (double)C[t];
    __syncthreads();

    const int tid = blockIdx.x * 256 + t;   // 0..131071
    const int b   = tid >> 14;              // 16384 threads per batch image
    const int p   = tid & 16383;            // float4 index within the image
    const int n0  = p << 2;

    const float4* __restrict__ Fb = (const float4*)(F + (size_t)b * CHN * NPIX);

    // fp64 accumulation: matched the reference last round (absmax 0.0625 pass)
    double d0[4] = {0.0, 0.0, 0.0, 0.0};
    double d1[4] = {0.0, 0.0, 0.0, 0.0};

    for (int cb = 0; cb < CHN; cb += 8) {
        float4 x[8];
        #pragma unroll
        for (int j = 0; j < 8; ++j)
            x[j] = Fb[(size_t)(cb + j) * (NPIX / 4) + p];   // 8 loads issued back-to-back
        #pragma unroll
        for (int j = 0; j < 8; ++j) {
            double a0 = c0s[cb + j], a1 = c1s[cb + j];
            double x0 = (double)x[j].x, x1 = (double)x[j].y;
            double x2 = (double)x[j].z, x3 = (double)x[j].w;
            d0[0] = fma(x0, a0, d0[0]);  d1[0] = fma(x0, a1, d1[0]);
            d0[1] = fma(x1, a0, d0[1]);  d1[1] = fma(x1, a1, d1[1]);
            d0[2] = fma(x2, a0, d0[2]);  d1[2] = fma(x2, a1, d1[2]);
            d0[3] = fma(x3, a0, d0[3]);  d1[3] = fma(x3, a1, d1[3]);
        }
    }

    float labf[4], dist0[4], dist1[4];
    #pragma unroll
    for (int j = 0; j < 4; ++j) {
        double dd0 = 0.5 * (1.0 - d0[j]);
        double dd1 = 0.5 * (1.0 - d1[j]);
        int lab = (dd1 < dd0) ? 1 : 0;   // argmin, ties -> 0
        labf[j]  = (float)lab;
        dist0[j] = (float)dd0;
        dist1[j] = (float)dd1;
    }

    float4 lab4 = make_float4(labf[0], labf[1], labf[2], labf[3]);
    *(float4*)(out + OFF_LABELS + b * NPIX + n0) = lab4;
    *(float4*)(out + OFF_LABELT + b * NPIX + n0) = lab4;

    const size_t obase = (size_t)OFF_ONEHOT + (size_t)b * (2 * NPIX) + 2 * n0;
    *(float4*)(out + obase)     = make_float4(1.0f - labf[0], labf[0], 1.0f - labf[1], labf[1]);
    *(float4*)(out + obase + 4) = make_float4(1.0f - labf[2], labf[2], 1.0f - labf[3], labf[3]);

    const size_t dbase = (size_t)OFF_DISTS + (size_t)b * (2 * NPIX) + 2 * n0;
    *(float4*)(out + dbase)     = make_float4(dist0[0], dist1[0], dist0[1], dist1[1]);
    *(float4*)(out + dbase + 4) = make_float4(dist0[2], dist1[2], dist0[3], dist1[3]);
}

// ---------------------------------------------------------------------------
// Pass 2 (fused sum+final, no ws, no atomics, no memset):
// one block per channel. Block ch reduces F[7][ch][:] masked by labels[7]
// (just written, LLC-hot) plus the global class-1 count, then writes its two
// center outputs directly.
// ---------------------------------------------------------------------------
__global__ __launch_bounds__(256) void center_pass(
    const float* __restrict__ F, const float* __restrict__ C, float* __restrict__ out)
{
    const int ch = blockIdx.x;          // 0..127
    const int t  = threadIdx.x;

    const float4* __restrict__ Fc = (const float4*)(F + (size_t)(7 * CHN + ch) * NPIX);
    const float4* __restrict__ L  = (const float4*)(out + OFF_LABELS + 7 * NPIX);

    double s_all = 0.0, s1 = 0.0;
    float  cntf  = 0.0f;                // exact: integer counts << 2^24

    #pragma unroll 4
    for (int i = t; i < NPIX / 4; i += 256) {   // 64 iterations
        float4 x = Fc[i];
        float4 l = L[i];                         // components exactly 0.0 or 1.0
        s_all += (double)x.x + (double)x.y + (double)x.z + (double)x.w;
        s1 += (double)(l.x * x.x) + (double)(l.y * x.y)
            + (double)(l.z * x.z) + (double)(l.w * x.w);
        cntf += l.x + l.y + l.z + l.w;
    }

    #pragma unroll
    for (int off = 32; off > 0; off >>= 1) {
        s_all += __shfl_down(s_all, off, 64);
        s1    += __shfl_down(s1,    off, 64);
        cntf  += __shfl_down(cntf,  off, 64);
    }

    __shared__ double redA[4], redS[4], redC[4];
    const int wave = t >> 6, lane = t & 63;
    if (lane == 0) { redA[wave] = s_all; redS[wave] = s1; redC[wave] = (double)cntf; }
    __syncthreads();
    if (t == 0) {
        double A    = redA[0] + redA[1] + redA[2] + redA[3];
        double S1   = redS[0] + redS[1] + redS[2] + redS[3];
        double cnt1 = redC[0] + redC[1] + redC[2] + redC[3];
        double Num0 = ((double)NPIX - cnt1) + 1.0;
        double Num1 = cnt1 + 1.0;
        double ci0  = (A - S1) / Num0;           // class-0 masked mean
        double ci1  = S1 / Num1;                 // class-1 masked mean
        double c0   = (double)C[ch];
        double c1   = (double)C[CHN + ch];
        out[OFF_CENTERS + ch]       = (float)(c0 + 0.001 * (ci0 - c0));
        out[OFF_CENTERS + CHN + ch] = (float)(c1 + 0.001 * (ci1 - c1));
    }
}

extern "C" void kernel_launch(void* const* d_in, const int* in_sizes, int n_in,
                              void* d_out, int out_size, void* d_ws, size_t ws_size,
                              hipStream_t stream) {
    const float* F = (const float*)d_in[0];   // FeatureT (8,128,256,256)
    const float* C = (const float*)d_in[1];   // centerInit (2,128)
    float* out = (float*)d_out;

    main_pass<<<dim3(512), dim3(256), 0, stream>>>(F, C, out);
    center_pass<<<dim3(128), dim3(256), 0, stream>>>(F, C, out);
}

// Round 3
// 374.651 us; speedup vs baseline: 1.0463x; 1.0175x over previous
//
#include <hip/hip_runtime.h>

// Problem constants (from reference): FeatureT (8,128,256,256) f32, centerInit (2,128) f32
#define BB      8
#define CHN     128
#define NPIX    65536           // 256*256

// Output flat offsets (floats), concatenated in return order
#define OFF_CENTERS 0                       // [2,128]            = 256
#define OFF_LABELS  256                     // [8,1,256,256]      = 524288
#define OFF_ONEHOT  (256 + 524288)          // [8,2,256,256] raw  = 1048576
#define OFF_DISTS   (OFF_ONEHOT + 1048576)  // [8,2,256,256] raw  = 1048576
#define OFF_LABELT  (OFF_DISTS + 1048576)   // [8,1,256,256]      = 524288

// ---------------------------------------------------------------------------
// Pass 1: dists, labels, onehot for all 8 batches. 4 pixels per thread.
// Explicit DOUBLE-BUFFERED loads: the next 8 float4 loads are issued before
// the current 8-channel fp64 compute block, so each SIMD keeps >=16 KB of
// reads in flight continuously (BDP ~9 KB at 2 waves/SIMD).
// ---------------------------------------------------------------------------
__global__ __launch_bounds__(256) void main_pass(
    const float* __restrict__ F, const float* __restrict__ C, float* __restrict__ out)
{
    __shared__ double c0s[CHN], c1s[CHN];
    const int t = threadIdx.x;
    if (t < 128)  c0s[t]       = (double)C[t];
    else          c1s[t - 128] = (double)C[t];
    __syncthreads();

    const int tid = blockIdx.x * 256 + t;   // 0..131071
    const int b   = tid >> 14;              // 16384 threads per batch image
    const int p   = tid & 16383;            // float4 index within the image
    const int n0  = p << 2;

    const float4* __restrict__ Fb = (const float4*)(F + (size_t)b * CHN * NPIX);

    // fp64 accumulation: argmin sign must match the fp64 numpy reference
    double d0[4] = {0.0, 0.0, 0.0, 0.0};
    double d1[4] = {0.0, 0.0, 0.0, 0.0};

    float4 xa[8], xb[8];
    #pragma unroll
    for (int j = 0; j < 8; ++j)
        xa[j] = Fb[j * (NPIX / 4) + p];     // prime buffer A (cb = 0)

    #pragma unroll
    for (int cb = 0; cb < CHN; cb += 8) {
        float4* cur = ((cb >> 3) & 1) ? xb : xa;   // static after full unroll
        float4* nxt = ((cb >> 3) & 1) ? xa : xb;
        if (cb + 8 < CHN) {
            #pragma unroll
            for (int j = 0; j < 8; ++j)
                nxt[j] = Fb[(cb + 8 + j) * (NPIX / 4) + p];   // prefetch next batch
        }
        #pragma unroll
        for (int j = 0; j < 8; ++j) {
            double a0 = c0s[cb + j], a1 = c1s[cb + j];
            double x0 = (double)cur[j].x, x1 = (double)cur[j].y;
            double x2 = (double)cur[j].z, x3 = (double)cur[j].w;
            d0[0] = fma(x0, a0, d0[0]);  d1[0] = fma(x0, a1, d1[0]);
            d0[1] = fma(x1, a0, d0[1]);  d1[1] = fma(x1, a1, d1[1]);
            d0[2] = fma(x2, a0, d0[2]);  d1[2] = fma(x2, a1, d1[2]);
            d0[3] = fma(x3, a0, d0[3]);  d1[3] = fma(x3, a1, d1[3]);
        }
    }

    float labf[4], dist0[4], dist1[4];
    #pragma unroll
    for (int j = 0; j < 4; ++j) {
        double dd0 = 0.5 * (1.0 - d0[j]);
        double dd1 = 0.5 * (1.0 - d1[j]);
        int lab = (dd1 < dd0) ? 1 : 0;   // argmin, ties -> 0
        labf[j]  = (float)lab;
        dist0[j] = (float)dd0;
        dist1[j] = (float)dd1;
    }

    float4 lab4 = make_float4(labf[0], labf[1], labf[2], labf[3]);
    *(float4*)(out + OFF_LABELS + b * NPIX + n0) = lab4;
    *(float4*)(out + OFF_LABELT + b * NPIX + n0) = lab4;

    const size_t obase = (size_t)OFF_ONEHOT + (size_t)b * (2 * NPIX) + 2 * n0;
    *(float4*)(out + obase)     = make_float4(1.0f - labf[0], labf[0], 1.0f - labf[1], labf[1]);
    *(float4*)(out + obase + 4) = make_float4(1.0f - labf[2], labf[2], 1.0f - labf[3], labf[3]);

    const size_t dbase = (size_t)OFF_DISTS + (size_t)b * (2 * NPIX) + 2 * n0;
    *(float4*)(out + dbase)     = make_float4(dist0[0], dist1[0], dist0[1], dist1[1]);
    *(float4*)(out + dbase + 4) = make_float4(dist0[2], dist1[2], dist0[3], dist1[3]);
}

// ---------------------------------------------------------------------------
// Pass 2 (fused sum+final): one 1024-thread block per channel (16 iterations,
// short tail). Reduces F[7][ch][:] masked by labels[7] (LLC-hot) plus the
// class-1 count, then writes its two center outputs directly.
// ---------------------------------------------------------------------------
__global__ __launch_bounds__(1024) void center_pass(
    const float* __restrict__ F, const float* __restrict__ C, float* __restrict__ out)
{
    const int ch = blockIdx.x;          // 0..127
    const int t  = threadIdx.x;         // 0..1023

    const float4* __restrict__ Fc = (const float4*)(F + (size_t)(7 * CHN + ch) * NPIX);
    const float4* __restrict__ L  = (const float4*)(out + OFF_LABELS + 7 * NPIX);

    double s_all = 0.0, s1 = 0.0;
    float  cntf  = 0.0f;                // exact: integer counts << 2^24

    #pragma unroll
    for (int i = 0; i < 16; ++i) {      // NPIX/4 / 1024 = 16
        int idx = t + i * 1024;
        float4 x = Fc[idx];
        float4 l = L[idx];              // components exactly 0.0 or 1.0
        s_all += (double)x.x + (double)x.y + (double)x.z + (double)x.w;
        s1 += (double)(l.x * x.x) + (double)(l.y * x.y)
            + (double)(l.z * x.z) + (double)(l.w * x.w);
        cntf += l.x + l.y + l.z + l.w;
    }

    #pragma unroll
    for (int off = 32; off > 0; off >>= 1) {
        s_all += __shfl_down(s_all, off, 64);
        s1    += __shfl_down(s1,    off, 64);
        cntf  += __shfl_down(cntf,  off, 64);
    }

    __shared__ double redA[16], redS[16], redC[16];
    const int wave = t >> 6, lane = t & 63;
    if (lane == 0) { redA[wave] = s_all; redS[wave] = s1; redC[wave] = (double)cntf; }
    __syncthreads();
    if (t == 0) {
        double A = 0.0, S1 = 0.0, cnt1 = 0.0;
        #pragma unroll
        for (int w = 0; w < 16; ++w) { A += redA[w]; S1 += redS[w]; cnt1 += redC[w]; }
        double Num0 = ((double)NPIX - cnt1) + 1.0;
        double Num1 = cnt1 + 1.0;
        double ci0  = (A - S1) / Num0;           // class-0 masked mean
        double ci1  = S1 / Num1;                 // class-1 masked mean
        double c0   = (double)C[ch];
        double c1   = (double)C[CHN + ch];
        out[OFF_CENTERS + ch]       = (float)(c0 + 0.001 * (ci0 - c0));
        out[OFF_CENTERS + CHN + ch] = (float)(c1 + 0.001 * (ci1 - c1));
    }
}

extern "C" void kernel_launch(void* const* d_in, const int* in_sizes, int n_in,
                              void* d_out, int out_size, void* d_ws, size_t ws_size,
                              hipStream_t stream) {
    const float* F = (const float*)d_in[0];   // FeatureT (8,128,256,256)
    const float* C = (const float*)d_in[1];   // centerInit (2,128)
    float* out = (float*)d_out;

    main_pass<<<dim3(512), dim3(256), 0, stream>>>(F, C, out);
    center_pass<<<dim3(128), dim3(1024), 0, stream>>>(F, C, out);
}